// Round 1
// baseline (1847.768 us; speedup 1.0000x reference)
//
#include <hip/hip_runtime.h>

#define NN 100000
#define NE 1600000

// ---------------------------------------------------------------------------
// GEMM: Y[N,M] = act(X[N,128]) @ W[128,M] + b   (act = relu if RELU_IN)
// Block: 256 threads, tile = ROWS x M. LDS: xt (transposed X tile) + half of W.
// Thread computes a 4x4 register tile; both LDS reads are b128-friendly.
// ---------------------------------------------------------------------------
template <int M, int ROWS, bool RELU_IN>
__global__ __launch_bounds__(256) void gemm_kernel(
    const float* __restrict__ X, const float* __restrict__ W,
    const float* __restrict__ b, float* __restrict__ Y, int N)
{
    constexpr int K  = 128;
    constexpr int CG = M / 4;        // col groups (4 cols each)
    constexpr int RG = 256 / CG;     // row groups
    constexpr int RPT = ROWS / RG;   // rows per thread
    static_assert(RPT == 4, "expect 4 rows per thread");

    __shared__ float xt[K * ROWS];   // [k][r]  (transposed)
    __shared__ float Ws[64 * M];     // half of W: [kk][m]

    const int tid  = threadIdx.x;
    const int row0 = blockIdx.x * ROWS;

    // ---- stage X tile, transposed, relu fused -----------------------------
    for (int i = tid; i < ROWS * (K / 4); i += 256) {
        int r  = i % ROWS;
        int k4 = i / ROWS;
        int rr = row0 + r;
        if (rr >= N) rr = N - 1;               // clamp (stores are guarded)
        float4 v = reinterpret_cast<const float4*>(X)[rr * (K / 4) + k4];
        if (RELU_IN) {
            v.x = fmaxf(v.x, 0.f); v.y = fmaxf(v.y, 0.f);
            v.z = fmaxf(v.z, 0.f); v.w = fmaxf(v.w, 0.f);
        }
        xt[(k4 * 4 + 0) * ROWS + r] = v.x;
        xt[(k4 * 4 + 1) * ROWS + r] = v.y;
        xt[(k4 * 4 + 2) * ROWS + r] = v.z;
        xt[(k4 * 4 + 3) * ROWS + r] = v.w;
    }

    const int cg = tid % CG;
    const int rg = tid / CG;
    const int c0 = cg * 4;
    const int r0 = rg * RPT;

    float acc[4][4];
    {
        float4 bv = reinterpret_cast<const float4*>(b)[cg];
        #pragma unroll
        for (int i = 0; i < 4; ++i) {
            acc[i][0] = bv.x; acc[i][1] = bv.y; acc[i][2] = bv.z; acc[i][3] = bv.w;
        }
    }

    for (int kh = 0; kh < 2; ++kh) {
        __syncthreads();
        // stage half of W: rows [kh*64, kh*64+64)
        for (int i = tid; i < 64 * (M / 4); i += 256) {
            reinterpret_cast<float4*>(Ws)[i] =
                reinterpret_cast<const float4*>(W)[kh * 64 * (M / 4) + i];
        }
        __syncthreads();

        #pragma unroll 4
        for (int kk = 0; kk < 64; ++kk) {
            const int k = kh * 64 + kk;
            float4 xv = *reinterpret_cast<const float4*>(&xt[k * ROWS + r0]);
            float4 wv = *reinterpret_cast<const float4*>(&Ws[kk * M + c0]);
            acc[0][0] += xv.x * wv.x; acc[0][1] += xv.x * wv.y;
            acc[0][2] += xv.x * wv.z; acc[0][3] += xv.x * wv.w;
            acc[1][0] += xv.y * wv.x; acc[1][1] += xv.y * wv.y;
            acc[1][2] += xv.y * wv.z; acc[1][3] += xv.y * wv.w;
            acc[2][0] += xv.z * wv.x; acc[2][1] += xv.z * wv.y;
            acc[2][2] += xv.z * wv.z; acc[2][3] += xv.z * wv.w;
            acc[3][0] += xv.w * wv.x; acc[3][1] += xv.w * wv.y;
            acc[3][2] += xv.w * wv.z; acc[3][3] += xv.w * wv.w;
        }
    }

    #pragma unroll
    for (int i = 0; i < 4; ++i) {
        int rr = row0 + r0 + i;
        if (rr < N) {
            float4 o = make_float4(acc[i][0], acc[i][1], acc[i][2], acc[i][3]);
            *reinterpret_cast<float4*>(&Y[rr * M + c0]) = o;
        }
    }
}

// ---------------------------------------------------------------------------
// COO scatter spmm: out[rows[e]] += vals[e] * Z[cols[e]]   (out pre-zeroed)
// 64 lanes per edge; D=128 -> float2 per lane, D=64 -> float per lane.
// ---------------------------------------------------------------------------
template <int D>
__global__ __launch_bounds__(256) void spmm_scatter(
    const int* __restrict__ rows, const int* __restrict__ cols,
    const float* __restrict__ vals, const float* __restrict__ Z,
    float* __restrict__ out)
{
    const unsigned gid = blockIdx.x * 256u + threadIdx.x;
    const unsigned total = (unsigned)NE * 64u;
    if (gid >= total) return;
    const int e = (int)(gid >> 6);
    const int l = (int)(gid & 63u);

    const int   r = rows[e];
    const int   c = cols[e];
    const float v = vals[e];

    if (D == 128) {
        float2 z = *reinterpret_cast<const float2*>(&Z[c * 128 + l * 2]);
        unsafeAtomicAdd(&out[r * 128 + l * 2 + 0], v * z.x);
        unsafeAtomicAdd(&out[r * 128 + l * 2 + 1], v * z.y);
    } else {
        float z = Z[c * 64 + l];
        unsafeAtomicAdd(&out[r * 64 + l], v * z);
    }
}

// ---------------------------------------------------------------------------
extern "C" void kernel_launch(void* const* d_in, const int* in_sizes, int n_in,
                              void* d_out, int out_size, void* d_ws, size_t ws_size,
                              hipStream_t stream)
{
    const int*   rows = (const int*)  d_in[0];
    const int*   cols = (const int*)  d_in[1];
    const float* vals = (const float*)d_in[2];
    const float* x    = (const float*)d_in[3];
    const float* W1   = (const float*)d_in[4];
    const float* b1   = (const float*)d_in[5];
    const float* W2   = (const float*)d_in[6];
    const float* b2   = (const float*)d_in[7];
    float* out = (float*)d_out;

    char* ws = (char*)d_ws;
    float* h  = (float*)ws;                                  // [N,128] then [N,64]
    float* s1 = (float*)(ws + (size_t)NN * 128 * sizeof(float)); // [N,128]
    // ws needed: 2 * 51.2 MB = 102.4 MB

    hipMemsetAsync(s1,  0, (size_t)NN * 128 * sizeof(float), stream);
    hipMemsetAsync(out, 0, (size_t)NN * 64  * sizeof(float), stream);

    // h1 = x @ W1 + b1
    gemm_kernel<128, 32, false><<<NN / 32, 256, 0, stream>>>(x, W1, b1, h, NN);

    // s1 = A @ h1
    {
        const unsigned total = (unsigned)NE * 64u;
        spmm_scatter<128><<<(total + 255u) / 256u, 256, 0, stream>>>(rows, cols, vals, h, s1);
    }

    // h2 = relu(s1) @ W2 + b2
    gemm_kernel<64, 64, true><<<(NN + 63) / 64, 256, 0, stream>>>(s1, W2, b2, h, NN);

    // out = A @ h2
    {
        const unsigned total = (unsigned)NE * 64u;
        spmm_scatter<64><<<(total + 255u) / 256u, 256, 0, stream>>>(rows, cols, vals, h, out);
    }
}

// Round 2
// 559.588 us; speedup vs baseline: 3.3020x; 3.3020x over previous
//
#include <hip/hip_runtime.h>

#define NN 100000
#define NE 1600000
#define SCAN_BLK 256
#define NBLK ((NN + SCAN_BLK - 1) / SCAN_BLK)   // 391

// ---------------------------------------------------------------------------
// GEMM: Y[N,M] = act(X[N,128]) @ W[128,M] + b   (act = relu if RELU_IN)
// ---------------------------------------------------------------------------
template <int M, int ROWS, bool RELU_IN>
__global__ __launch_bounds__(256) void gemm_kernel(
    const float* __restrict__ X, const float* __restrict__ W,
    const float* __restrict__ b, float* __restrict__ Y, int N)
{
    constexpr int K  = 128;
    constexpr int CG = M / 4;        // col groups (4 cols each)
    constexpr int RG = 256 / CG;     // row groups
    constexpr int RPT = ROWS / RG;   // rows per thread
    static_assert(RPT == 4, "expect 4 rows per thread");

    __shared__ float xt[K * ROWS];   // [k][r]  (transposed)
    __shared__ float Ws[64 * M];     // half of W: [kk][m]

    const int tid  = threadIdx.x;
    const int row0 = blockIdx.x * ROWS;

    for (int i = tid; i < ROWS * (K / 4); i += 256) {
        int r  = i % ROWS;
        int k4 = i / ROWS;
        int rr = row0 + r;
        if (rr >= N) rr = N - 1;               // clamp (stores are guarded)
        float4 v = reinterpret_cast<const float4*>(X)[rr * (K / 4) + k4];
        if (RELU_IN) {
            v.x = fmaxf(v.x, 0.f); v.y = fmaxf(v.y, 0.f);
            v.z = fmaxf(v.z, 0.f); v.w = fmaxf(v.w, 0.f);
        }
        xt[(k4 * 4 + 0) * ROWS + r] = v.x;
        xt[(k4 * 4 + 1) * ROWS + r] = v.y;
        xt[(k4 * 4 + 2) * ROWS + r] = v.z;
        xt[(k4 * 4 + 3) * ROWS + r] = v.w;
    }

    const int cg = tid % CG;
    const int rg = tid / CG;
    const int c0 = cg * 4;
    const int r0 = rg * RPT;

    float acc[4][4];
    {
        float4 bv = reinterpret_cast<const float4*>(b)[cg];
        #pragma unroll
        for (int i = 0; i < 4; ++i) {
            acc[i][0] = bv.x; acc[i][1] = bv.y; acc[i][2] = bv.z; acc[i][3] = bv.w;
        }
    }

    for (int kh = 0; kh < 2; ++kh) {
        __syncthreads();
        for (int i = tid; i < 64 * (M / 4); i += 256) {
            reinterpret_cast<float4*>(Ws)[i] =
                reinterpret_cast<const float4*>(W)[kh * 64 * (M / 4) + i];
        }
        __syncthreads();

        #pragma unroll 4
        for (int kk = 0; kk < 64; ++kk) {
            const int k = kh * 64 + kk;
            float4 xv = *reinterpret_cast<const float4*>(&xt[k * ROWS + r0]);
            float4 wv = *reinterpret_cast<const float4*>(&Ws[kk * M + c0]);
            acc[0][0] += xv.x * wv.x; acc[0][1] += xv.x * wv.y;
            acc[0][2] += xv.x * wv.z; acc[0][3] += xv.x * wv.w;
            acc[1][0] += xv.y * wv.x; acc[1][1] += xv.y * wv.y;
            acc[1][2] += xv.y * wv.z; acc[1][3] += xv.y * wv.w;
            acc[2][0] += xv.z * wv.x; acc[2][1] += xv.z * wv.y;
            acc[2][2] += xv.z * wv.z; acc[2][3] += xv.z * wv.w;
            acc[3][0] += xv.w * wv.x; acc[3][1] += xv.w * wv.y;
            acc[3][2] += xv.w * wv.z; acc[3][3] += xv.w * wv.w;
        }
    }

    #pragma unroll
    for (int i = 0; i < 4; ++i) {
        int rr = row0 + r0 + i;
        if (rr < N) {
            float4 o = make_float4(acc[i][0], acc[i][1], acc[i][2], acc[i][3]);
            *reinterpret_cast<float4*>(&Y[rr * M + c0]) = o;
        }
    }
}

// ---------------------------------------------------------------------------
// CSR build: histogram -> block scan -> scan of block sums -> add base -> scatter
// ---------------------------------------------------------------------------
__global__ __launch_bounds__(256) void hist_kernel(
    const int* __restrict__ rows, int* __restrict__ counts)
{
    int e = blockIdx.x * 256 + threadIdx.x;
    if (e < NE) atomicAdd(&counts[rows[e]], 1);
}

// Per-block exclusive scan of counts; write partial to row_ptr, block sum out.
__global__ __launch_bounds__(SCAN_BLK) void scan_block_kernel(
    const int* __restrict__ counts, int* __restrict__ row_ptr,
    int* __restrict__ bsums)
{
    __shared__ int s[SCAN_BLK];
    const int tid = threadIdx.x;
    const int i   = blockIdx.x * SCAN_BLK + tid;
    int v = (i < NN) ? counts[i] : 0;
    s[tid] = v;
    __syncthreads();
    for (int off = 1; off < SCAN_BLK; off <<= 1) {
        int t = (tid >= off) ? s[tid - off] : 0;
        __syncthreads();
        s[tid] += t;
        __syncthreads();
    }
    if (i < NN) row_ptr[i] = s[tid] - v;          // exclusive, no base yet
    if (tid == SCAN_BLK - 1) bsums[blockIdx.x] = s[tid];
}

// Single-block exclusive scan of the NBLK block sums.
__global__ __launch_bounds__(512) void scan_sums_kernel(int* __restrict__ bsums)
{
    __shared__ int s[512];
    const int tid = threadIdx.x;
    int v = (tid < NBLK) ? bsums[tid] : 0;
    s[tid] = v;
    __syncthreads();
    for (int off = 1; off < 512; off <<= 1) {
        int t = (tid >= off) ? s[tid - off] : 0;
        __syncthreads();
        s[tid] += t;
        __syncthreads();
    }
    if (tid < NBLK) bsums[tid] = s[tid] - v;      // exclusive
}

__global__ __launch_bounds__(SCAN_BLK) void add_base_kernel(
    int* __restrict__ row_ptr, const int* __restrict__ bsums)
{
    const int i = blockIdx.x * SCAN_BLK + threadIdx.x;
    if (i < NN) row_ptr[i] += bsums[blockIdx.x];
    else if (i == NN) row_ptr[NN] = NE;
}

__global__ __launch_bounds__(256) void scatter_edges_kernel(
    const int* __restrict__ rows, const int* __restrict__ cols,
    const float* __restrict__ vals, const int* __restrict__ row_ptr,
    int* __restrict__ fill, int* __restrict__ cols_s, float* __restrict__ vals_s)
{
    int e = blockIdx.x * 256 + threadIdx.x;
    if (e >= NE) return;
    const int r = rows[e];
    const int pos = row_ptr[r] + atomicAdd(&fill[r], 1);
    cols_s[pos] = cols[e];
    vals_s[pos] = vals[e];
}

// ---------------------------------------------------------------------------
// Gather spmm: one wave per output row. Coalesced (col,val) chunk loads,
// __shfl broadcast, 4x-unrolled random row gathers of Z (L2/L3 resident).
// ---------------------------------------------------------------------------
template <int D>
__global__ __launch_bounds__(256) void spmm_gather(
    const int* __restrict__ row_ptr, const int* __restrict__ cols_s,
    const float* __restrict__ vals_s, const float* __restrict__ Z,
    float* __restrict__ out)
{
    const int row  = (blockIdx.x * 256 + threadIdx.x) >> 6;
    const int lane = threadIdx.x & 63;
    if (row >= NN) return;
    const int start = row_ptr[row];
    const int end   = row_ptr[row + 1];

    float accx = 0.f, accy = 0.f;

    for (int base = start; base < end; base += 64) {
        const int m = min(end - base, 64);
        int c = 0; float v = 0.f;
        if (lane < m) { c = cols_s[base + lane]; v = vals_s[base + lane]; }

        int j = 0;
        for (; j + 4 <= m; j += 4) {
            int   c0 = __shfl(c, j + 0), c1 = __shfl(c, j + 1);
            int   c2 = __shfl(c, j + 2), c3 = __shfl(c, j + 3);
            float v0 = __shfl(v, j + 0), v1 = __shfl(v, j + 1);
            float v2 = __shfl(v, j + 2), v3 = __shfl(v, j + 3);
            if (D == 128) {
                float2 z0 = *reinterpret_cast<const float2*>(&Z[c0 * 128 + 2 * lane]);
                float2 z1 = *reinterpret_cast<const float2*>(&Z[c1 * 128 + 2 * lane]);
                float2 z2 = *reinterpret_cast<const float2*>(&Z[c2 * 128 + 2 * lane]);
                float2 z3 = *reinterpret_cast<const float2*>(&Z[c3 * 128 + 2 * lane]);
                accx += v0 * z0.x; accy += v0 * z0.y;
                accx += v1 * z1.x; accy += v1 * z1.y;
                accx += v2 * z2.x; accy += v2 * z2.y;
                accx += v3 * z3.x; accy += v3 * z3.y;
            } else {
                float z0 = Z[c0 * 64 + lane];
                float z1 = Z[c1 * 64 + lane];
                float z2 = Z[c2 * 64 + lane];
                float z3 = Z[c3 * 64 + lane];
                accx += v0 * z0 + v1 * z1;
                accx += v2 * z2 + v3 * z3;
            }
        }
        for (; j < m; ++j) {
            int   cj = __shfl(c, j);
            float vj = __shfl(v, j);
            if (D == 128) {
                float2 z = *reinterpret_cast<const float2*>(&Z[cj * 128 + 2 * lane]);
                accx += vj * z.x; accy += vj * z.y;
            } else {
                accx += vj * Z[cj * 64 + lane];
            }
        }
    }

    if (D == 128)
        *reinterpret_cast<float2*>(&out[row * 128 + 2 * lane]) = make_float2(accx, accy);
    else
        out[row * 64 + lane] = accx;
}

// ---------------------------------------------------------------------------
extern "C" void kernel_launch(void* const* d_in, const int* in_sizes, int n_in,
                              void* d_out, int out_size, void* d_ws, size_t ws_size,
                              hipStream_t stream)
{
    const int*   rows = (const int*)  d_in[0];
    const int*   cols = (const int*)  d_in[1];
    const float* vals = (const float*)d_in[2];
    const float* x    = (const float*)d_in[3];
    const float* W1   = (const float*)d_in[4];
    const float* b1   = (const float*)d_in[5];
    const float* W2   = (const float*)d_in[6];
    const float* b2   = (const float*)d_in[7];
    float* out = (float*)d_out;

    char* ws = (char*)d_ws;
    size_t off = 0;
    float* h       = (float*)(ws + off); off += (size_t)NN * 128 * sizeof(float); // 51.2MB
    float* s1      = (float*)(ws + off); off += (size_t)NN * 128 * sizeof(float); // 51.2MB
    int*   cols_s  = (int*)  (ws + off); off += (size_t)NE * sizeof(int);         // 6.4MB
    float* vals_s  = (float*)(ws + off); off += (size_t)NE * sizeof(float);       // 6.4MB
    int*   row_ptr = (int*)  (ws + off); off += (size_t)(NN + 1) * sizeof(int);
    int*   counts  = (int*)  (ws + off); off += (size_t)NN * sizeof(int);
    int*   fill    = (int*)  (ws + off); off += (size_t)NN * sizeof(int);
    int*   bsums   = (int*)  (ws + off); off += (size_t)NBLK * sizeof(int);
    // total ~116.5 MB

    // ---- CSR build (A is shared by both layers; build once) ----
    hipMemsetAsync(counts, 0, (size_t)NN * sizeof(int), stream);
    hipMemsetAsync(fill,   0, (size_t)NN * sizeof(int), stream);
    hist_kernel<<<(NE + 255) / 256, 256, 0, stream>>>(rows, counts);
    scan_block_kernel<<<NBLK, SCAN_BLK, 0, stream>>>(counts, row_ptr, bsums);
    scan_sums_kernel<<<1, 512, 0, stream>>>(bsums);
    add_base_kernel<<<NBLK + 1, SCAN_BLK, 0, stream>>>(row_ptr, bsums);
    scatter_edges_kernel<<<(NE + 255) / 256, 256, 0, stream>>>(
        rows, cols, vals, row_ptr, fill, cols_s, vals_s);

    // ---- layer 1 ----
    gemm_kernel<128, 32, false><<<NN / 32, 256, 0, stream>>>(x, W1, b1, h, NN);
    spmm_gather<128><<<(NN * 64 + 255) / 256, 256, 0, stream>>>(row_ptr, cols_s, vals_s, h, s1);

    // ---- layer 2 ----
    gemm_kernel<64, 64, true><<<(NN + 63) / 64, 256, 0, stream>>>(s1, W2, b2, h, NN);
    spmm_gather<64><<<(NN * 64 + 255) / 256, 256, 0, stream>>>(row_ptr, cols_s, vals_s, h, out);
}

// Round 3
// 488.929 us; speedup vs baseline: 3.7792x; 1.1445x over previous
//
#include <hip/hip_runtime.h>

typedef unsigned int uint;
typedef unsigned short ushort;

#define NN 100000
#define NE 1600000
#define SCAN_BLK 256
#define NBLK ((NN + SCAN_BLK - 1) / SCAN_BLK)   // 391

// ---- bf16 helpers (RTNE, finite values only) ------------------------------
__device__ __forceinline__ ushort f2bf(float f) {
    uint u = __float_as_uint(f);
    u += 0x7FFFu + ((u >> 16) & 1u);
    return (ushort)(u >> 16);
}
__device__ __forceinline__ float bf2f(ushort h) {
    return __uint_as_float(((uint)h) << 16);
}

// ---------------------------------------------------------------------------
// GEMM: Y[N,M](bf16) = act(X[N,128]) @ W[128,M] + b    (act=relu if RELU_IN)
// TIN = float (f32 input) or ushort (bf16 input). f32 accumulate.
// ---------------------------------------------------------------------------
template <typename TIN, int M, int ROWS, bool RELU_IN>
__global__ __launch_bounds__(256) void gemm_kernel(
    const TIN* __restrict__ X, const float* __restrict__ W,
    const float* __restrict__ b, ushort* __restrict__ Y, int N)
{
    constexpr int K  = 128;
    constexpr int CG = M / 4;        // col groups (4 cols each)
    constexpr int RG = 256 / CG;     // row groups
    constexpr int RPT = ROWS / RG;   // rows per thread
    static_assert(RPT == 4, "expect 4 rows per thread");

    __shared__ float xt[K * ROWS];   // [k][r]  (transposed)
    __shared__ float Ws[64 * M];     // half of W: [kk][m]

    const int tid  = threadIdx.x;
    const int row0 = blockIdx.x * ROWS;

    for (int i = tid; i < ROWS * (K / 4); i += 256) {
        int r  = i % ROWS;
        int k4 = i / ROWS;
        int rr = row0 + r;
        if (rr >= N) rr = N - 1;               // clamp (stores are guarded)
        float v0, v1, v2, v3;
        if constexpr (sizeof(TIN) == 4) {
            float4 v = reinterpret_cast<const float4*>(X)[rr * (K / 4) + k4];
            v0 = v.x; v1 = v.y; v2 = v.z; v3 = v.w;
        } else {
            ushort4 v = reinterpret_cast<const ushort4*>(X)[rr * (K / 4) + k4];
            v0 = bf2f(v.x); v1 = bf2f(v.y); v2 = bf2f(v.z); v3 = bf2f(v.w);
        }
        if (RELU_IN) {
            v0 = fmaxf(v0, 0.f); v1 = fmaxf(v1, 0.f);
            v2 = fmaxf(v2, 0.f); v3 = fmaxf(v3, 0.f);
        }
        xt[(k4 * 4 + 0) * ROWS + r] = v0;
        xt[(k4 * 4 + 1) * ROWS + r] = v1;
        xt[(k4 * 4 + 2) * ROWS + r] = v2;
        xt[(k4 * 4 + 3) * ROWS + r] = v3;
    }

    const int cg = tid % CG;
    const int rg = tid / CG;
    const int c0 = cg * 4;
    const int r0 = rg * RPT;

    float acc[4][4];
    {
        float4 bv = reinterpret_cast<const float4*>(b)[cg];
        #pragma unroll
        for (int i = 0; i < 4; ++i) {
            acc[i][0] = bv.x; acc[i][1] = bv.y; acc[i][2] = bv.z; acc[i][3] = bv.w;
        }
    }

    for (int kh = 0; kh < 2; ++kh) {
        __syncthreads();
        for (int i = tid; i < 64 * (M / 4); i += 256) {
            reinterpret_cast<float4*>(Ws)[i] =
                reinterpret_cast<const float4*>(W)[kh * 64 * (M / 4) + i];
        }
        __syncthreads();

        #pragma unroll 4
        for (int kk = 0; kk < 64; ++kk) {
            const int k = kh * 64 + kk;
            float4 xv = *reinterpret_cast<const float4*>(&xt[k * ROWS + r0]);
            float4 wv = *reinterpret_cast<const float4*>(&Ws[kk * M + c0]);
            acc[0][0] += xv.x * wv.x; acc[0][1] += xv.x * wv.y;
            acc[0][2] += xv.x * wv.z; acc[0][3] += xv.x * wv.w;
            acc[1][0] += xv.y * wv.x; acc[1][1] += xv.y * wv.y;
            acc[1][2] += xv.y * wv.z; acc[1][3] += xv.y * wv.w;
            acc[2][0] += xv.z * wv.x; acc[2][1] += xv.z * wv.y;
            acc[2][2] += xv.z * wv.z; acc[2][3] += xv.z * wv.w;
            acc[3][0] += xv.w * wv.x; acc[3][1] += xv.w * wv.y;
            acc[3][2] += xv.w * wv.z; acc[3][3] += xv.w * wv.w;
        }
    }

    #pragma unroll
    for (int i = 0; i < 4; ++i) {
        int rr = row0 + r0 + i;
        if (rr < N) {
            ushort4 o;
            o.x = f2bf(acc[i][0]); o.y = f2bf(acc[i][1]);
            o.z = f2bf(acc[i][2]); o.w = f2bf(acc[i][3]);
            *reinterpret_cast<ushort4*>(&Y[rr * M + c0]) = o;
        }
    }
}

// ---------------------------------------------------------------------------
// CSR build
// ---------------------------------------------------------------------------
__global__ __launch_bounds__(256) void hist_kernel(
    const int* __restrict__ rows, int* __restrict__ counts)
{
    int t = blockIdx.x * 256 + threadIdx.x;
    if (t < NE / 4) {
        int4 r = reinterpret_cast<const int4*>(rows)[t];
        atomicAdd(&counts[r.x], 1); atomicAdd(&counts[r.y], 1);
        atomicAdd(&counts[r.z], 1); atomicAdd(&counts[r.w], 1);
    }
}

// Per-block scan: row_ptr[i] = exclusive prefix (partial), counts[i] = inclusive
// prefix (partial, becomes the bucket END pointer after base add).
__global__ __launch_bounds__(SCAN_BLK) void scan_block_kernel(
    int* __restrict__ counts, int* __restrict__ row_ptr, int* __restrict__ bsums)
{
    __shared__ int s[SCAN_BLK];
    const int tid = threadIdx.x;
    const int i   = blockIdx.x * SCAN_BLK + tid;
    int v = (i < NN) ? counts[i] : 0;
    s[tid] = v;
    __syncthreads();
    for (int off = 1; off < SCAN_BLK; off <<= 1) {
        int t = (tid >= off) ? s[tid - off] : 0;
        __syncthreads();
        s[tid] += t;
        __syncthreads();
    }
    if (i < NN) {
        row_ptr[i] = s[tid] - v;     // exclusive, no base
        counts[i]  = s[tid];         // inclusive, no base (end pointer)
    }
    if (tid == SCAN_BLK - 1) bsums[blockIdx.x] = s[tid];
}

__global__ __launch_bounds__(512) void scan_sums_kernel(int* __restrict__ bsums)
{
    __shared__ int s[512];
    const int tid = threadIdx.x;
    int v = (tid < NBLK) ? bsums[tid] : 0;
    s[tid] = v;
    __syncthreads();
    for (int off = 1; off < 512; off <<= 1) {
        int t = (tid >= off) ? s[tid - off] : 0;
        __syncthreads();
        s[tid] += t;
        __syncthreads();
    }
    if (tid < NBLK) bsums[tid] = s[tid] - v;      // exclusive
}

__global__ __launch_bounds__(SCAN_BLK) void add_base_kernel(
    int* __restrict__ row_ptr, int* __restrict__ counts,
    const int* __restrict__ bsums)
{
    const int i = blockIdx.x * SCAN_BLK + threadIdx.x;
    if (i < NN) {
        int base = bsums[blockIdx.x];
        row_ptr[i] += base;
        counts[i]  += base;          // now = row end pointer
    } else if (i == NN) {
        row_ptr[NN] = NE;
    }
}

// scatter: pos = --end[r]; es[pos] = {col, val_bits}. 4 edges/thread.
__global__ __launch_bounds__(256) void scatter_edges_kernel(
    const int* __restrict__ rows, const int* __restrict__ cols,
    const float* __restrict__ vals, int* __restrict__ endp,
    int2* __restrict__ es)
{
    int t = blockIdx.x * 256 + threadIdx.x;
    if (t >= NE / 4) return;
    int4   r = reinterpret_cast<const int4*>(rows)[t];
    int4   c = reinterpret_cast<const int4*>(cols)[t];
    float4 v = reinterpret_cast<const float4*>(vals)[t];
    int p0 = atomicSub(&endp[r.x], 1) - 1;
    int p1 = atomicSub(&endp[r.y], 1) - 1;
    int p2 = atomicSub(&endp[r.z], 1) - 1;
    int p3 = atomicSub(&endp[r.w], 1) - 1;
    es[p0] = make_int2(c.x, __float_as_int(v.x));
    es[p1] = make_int2(c.y, __float_as_int(v.y));
    es[p2] = make_int2(c.z, __float_as_int(v.z));
    es[p3] = make_int2(c.w, __float_as_int(v.w));
}

// ---------------------------------------------------------------------------
// Gather spmm: one wave per row; bf16 Z rows; f32 accumulate; f32 out.
// ---------------------------------------------------------------------------
template <int D>
__global__ __launch_bounds__(256) void spmm_gather(
    const int* __restrict__ row_ptr, const int2* __restrict__ es,
    const ushort* __restrict__ Zb, float* __restrict__ out)
{
    const int row  = (blockIdx.x * 256 + threadIdx.x) >> 6;
    const int lane = threadIdx.x & 63;
    if (row >= NN) return;
    const int start = row_ptr[row];
    const int end   = row_ptr[row + 1];

    float accx = 0.f, accy = 0.f;

    for (int base = start; base < end; base += 64) {
        const int m = min(end - base, 64);
        int c = 0, vb = 0;
        if (lane < m) { int2 e = es[base + lane]; c = e.x; vb = e.y; }

        int j = 0;
        for (; j + 4 <= m; j += 4) {
            int   c0 = __shfl(c, j + 0), c1 = __shfl(c, j + 1);
            int   c2 = __shfl(c, j + 2), c3 = __shfl(c, j + 3);
            float v0 = __int_as_float(__shfl(vb, j + 0));
            float v1 = __int_as_float(__shfl(vb, j + 1));
            float v2 = __int_as_float(__shfl(vb, j + 2));
            float v3 = __int_as_float(__shfl(vb, j + 3));
            if (D == 128) {
                uint z0 = *reinterpret_cast<const uint*>(&Zb[(size_t)c0 * 128 + 2 * lane]);
                uint z1 = *reinterpret_cast<const uint*>(&Zb[(size_t)c1 * 128 + 2 * lane]);
                uint z2 = *reinterpret_cast<const uint*>(&Zb[(size_t)c2 * 128 + 2 * lane]);
                uint z3 = *reinterpret_cast<const uint*>(&Zb[(size_t)c3 * 128 + 2 * lane]);
                accx += v0 * __uint_as_float(z0 << 16);
                accy += v0 * __uint_as_float(z0 & 0xFFFF0000u);
                accx += v1 * __uint_as_float(z1 << 16);
                accy += v1 * __uint_as_float(z1 & 0xFFFF0000u);
                accx += v2 * __uint_as_float(z2 << 16);
                accy += v2 * __uint_as_float(z2 & 0xFFFF0000u);
                accx += v3 * __uint_as_float(z3 << 16);
                accy += v3 * __uint_as_float(z3 & 0xFFFF0000u);
            } else {
                float z0 = bf2f(Zb[(size_t)c0 * 64 + lane]);
                float z1 = bf2f(Zb[(size_t)c1 * 64 + lane]);
                float z2 = bf2f(Zb[(size_t)c2 * 64 + lane]);
                float z3 = bf2f(Zb[(size_t)c3 * 64 + lane]);
                accx += v0 * z0 + v1 * z1;
                accx += v2 * z2 + v3 * z3;
            }
        }
        for (; j < m; ++j) {
            int   cj = __shfl(c, j);
            float vj = __int_as_float(__shfl(vb, j));
            if (D == 128) {
                uint z = *reinterpret_cast<const uint*>(&Zb[(size_t)cj * 128 + 2 * lane]);
                accx += vj * __uint_as_float(z << 16);
                accy += vj * __uint_as_float(z & 0xFFFF0000u);
            } else {
                accx += vj * bf2f(Zb[(size_t)cj * 64 + lane]);
            }
        }
    }

    if (D == 128)
        *reinterpret_cast<float2*>(&out[(size_t)row * 128 + 2 * lane]) = make_float2(accx, accy);
    else
        out[(size_t)row * 64 + lane] = accx;
}

// ---------------------------------------------------------------------------
extern "C" void kernel_launch(void* const* d_in, const int* in_sizes, int n_in,
                              void* d_out, int out_size, void* d_ws, size_t ws_size,
                              hipStream_t stream)
{
    const int*   rows = (const int*)  d_in[0];
    const int*   cols = (const int*)  d_in[1];
    const float* vals = (const float*)d_in[2];
    const float* x    = (const float*)d_in[3];
    const float* W1   = (const float*)d_in[4];
    const float* b1   = (const float*)d_in[5];
    const float* W2   = (const float*)d_in[6];
    const float* b2   = (const float*)d_in[7];
    float* out = (float*)d_out;

    char* ws = (char*)d_ws;
    size_t off = 0;
    ushort* h1b    = (ushort*)(ws + off); off += (size_t)NN * 128 * sizeof(ushort); // 25.6MB
    float*  s1     = (float*) (ws + off); off += (size_t)NN * 128 * sizeof(float);  // 51.2MB
    ushort* h2b    = (ushort*)(ws + off); off += (size_t)NN * 64 * sizeof(ushort);  // 12.8MB
    int2*   es     = (int2*)  (ws + off); off += (size_t)NE * sizeof(int2);         // 12.8MB
    int*    row_ptr= (int*)   (ws + off); off += (size_t)(NN + 1) * sizeof(int);
    int*    counts = (int*)   (ws + off); off += (size_t)NN * sizeof(int);
    int*    bsums  = (int*)   (ws + off); off += (size_t)NBLK * sizeof(int);
    // total ~103 MB

    // ---- CSR build (A shared by both layers) ----
    hipMemsetAsync(counts, 0, (size_t)NN * sizeof(int), stream);
    hist_kernel<<<(NE / 4 + 255) / 256, 256, 0, stream>>>(rows, counts);
    scan_block_kernel<<<NBLK, SCAN_BLK, 0, stream>>>(counts, row_ptr, bsums);
    scan_sums_kernel<<<1, 512, 0, stream>>>(bsums);
    add_base_kernel<<<NBLK, SCAN_BLK, 0, stream>>>(row_ptr, counts, bsums);
    scatter_edges_kernel<<<(NE / 4 + 255) / 256, 256, 0, stream>>>(
        rows, cols, vals, counts, es);

    // ---- layer 1 ----
    gemm_kernel<float, 128, 32, false><<<NN / 32, 256, 0, stream>>>(x, W1, b1, h1b, NN);
    spmm_gather<128><<<(NN * 64 + 255) / 256, 256, 0, stream>>>(row_ptr, es, h1b, s1);

    // ---- layer 2 ----  (relu fused into gemm2 staging; s1 stays f32)
    gemm_kernel<float, 64, 64, true><<<(NN + 63) / 64, 256, 0, stream>>>(
        s1, W2, b2, h2b, NN);
    spmm_gather<64><<<(NN * 64 + 255) / 256, 256, 0, stream>>>(row_ptr, es, h2b, out);
}